// Round 16
// baseline (1475.042 us; speedup 1.0000x reference)
//
#include <hip/hip_runtime.h>
#include <math.h>

#define N_NODES 10000
#define N_EDGES 320000
#define D 64
#define D_IN 128
#define D_OUT 16
#define NM (N_NODES * D)   // 640000 elements per state vector
#define GG_BLOCKS 256

// ---------------------------------------------------------------------------
// Fused setup: block 0 computes Theta = (I+Om)^-1 (I-Om); blocks 1..625 do
// enc (16 nodes each, one node per wave) + edge counting.
// Theta via 4x4-BLOCKED no-pivot Gauss-Jordan, 16 steps x 3 barriers.
// Phase A (4x4 diag-block inverse) is WAVE-PARALLEL via __shfl.
// No-pivot validity: every Schur complement of A = I + skew has symmetric
// part >= I, as does each leading 4x4 block.
// Theta stored TRANSPOSED: thetaT[k*64 + d] = Theta[d][k].
// ---------------------------------------------------------------------------
__global__ void __launch_bounds__(1024) setup_kernel(
    const float* __restrict__ B, float* __restrict__ thetaT,
    const float* __restrict__ x, const float* __restrict__ encW,
    const float* __restrict__ encb, float* __restrict__ b,
    float* __restrict__ x0, float* __restrict__ t0,
    const int* __restrict__ dst, int* __restrict__ counts) {
    __shared__ float sh[64 * 132 + 16];     // M (stride 132) + Dinv
    const int tid = threadIdx.x;

    if (blockIdx.x == 0) {
        float* Dinv = &sh[64 * 132];
        for (int i = tid; i < 64 * 128; i += 1024) {
            int r = i >> 7, c = i & 127;
            float v;
            if (c < 64) {
                float om = 0.5f * (B[r * 64 + c] - B[c * 64 + r]);
                v = om + (r == c ? 1.0f : 0.0f);
            } else {
                int c2 = c - 64;
                float om = 0.5f * (B[r * 64 + c2] - B[c2 * 64 + r]);
                v = -om + (r == c2 ? 1.0f : 0.0f);
            }
            sh[r * 132 + c] = v;
        }
        const int r  = tid >> 4;            // owned row (64)
        const int cb = (tid & 15) * 8;      // owned 8-col chunk (16)

        for (int kb = 0; kb < 16; ++kb) {
            const int kc = kb * 4;
            __syncthreads();
            // A: lanes 0..15 invert the 4x4 diag block, in-place GJ via shfl.
            if (tid < 16) {
                const int i = tid >> 2, j = tid & 3;
                float a = sh[(kc + i) * 132 + kc + j];
#pragma unroll
                for (int p = 0; p < 4; ++p) {
                    float app = __shfl(a, p * 5, 16);
                    float apj = __shfl(a, p * 4 + j, 16);
                    float aip = __shfl(a, i * 4 + p, 16);
                    float d = 1.0f / app;
                    float na;
                    if (i == p)      na = (j == p) ? d : a * d;
                    else if (j == p) na = -a * d;
                    else             na = fmaf(-aip * d, apj, a);
                    a = na;
                }
                Dinv[tid] = a;
            }
            __syncthreads();
            // B: pivot rows <- Dinv @ pivot rows, cols kc+4..127 (one col/thread)
            {
                int c = kc + 4 + tid;
                if (c < 128) {
                    float o0 = sh[(kc + 0) * 132 + c];
                    float o1 = sh[(kc + 1) * 132 + c];
                    float o2 = sh[(kc + 2) * 132 + c];
                    float o3 = sh[(kc + 3) * 132 + c];
#pragma unroll
                    for (int i = 0; i < 4; ++i) {
                        float n = Dinv[i * 4 + 0] * o0 + Dinv[i * 4 + 1] * o1 +
                                  Dinv[i * 4 + 2] * o2 + Dinv[i * 4 + 3] * o3;
                        sh[(kc + i) * 132 + c] = n;
                    }
                }
            }
            __syncthreads();
            // C: rank-4 eliminate rows outside block, cols > kc+3
            if (r < kc || r > kc + 3) {
                const float f0 = sh[r * 132 + kc + 0];
                const float f1 = sh[r * 132 + kc + 1];
                const float f2 = sh[r * 132 + kc + 2];
                const float f3 = sh[r * 132 + kc + 3];
                if (cb > kc + 3) {          // chunk fully beyond block: float4 path
#pragma unroll
                    for (int h = 0; h < 2; ++h) {
                        const int c = cb + h * 4;
                        float4 p0 = *(const float4*)&sh[(kc + 0) * 132 + c];
                        float4 p1 = *(const float4*)&sh[(kc + 1) * 132 + c];
                        float4 p2 = *(const float4*)&sh[(kc + 2) * 132 + c];
                        float4 p3 = *(const float4*)&sh[(kc + 3) * 132 + c];
                        float4 v  = *(float4*)&sh[r * 132 + c];
                        v.x = fmaf(-f3, p3.x, fmaf(-f2, p2.x, fmaf(-f1, p1.x, fmaf(-f0, p0.x, v.x))));
                        v.y = fmaf(-f3, p3.y, fmaf(-f2, p2.y, fmaf(-f1, p1.y, fmaf(-f0, p0.y, v.y))));
                        v.z = fmaf(-f3, p3.z, fmaf(-f2, p2.z, fmaf(-f1, p1.z, fmaf(-f0, p0.z, v.z))));
                        v.w = fmaf(-f3, p3.w, fmaf(-f2, p2.w, fmaf(-f1, p1.w, fmaf(-f0, p0.w, v.w))));
                        *(float4*)&sh[r * 132 + c] = v;
                    }
                } else if (cb + 7 > kc + 3) {  // straddling chunk: predicated scalar
#pragma unroll
                    for (int j = 0; j < 8; ++j) {
                        const int c = cb + j;
                        if (c > kc + 3) {
                            float v = sh[r * 132 + c];
                            v = fmaf(-f0, sh[(kc + 0) * 132 + c], v);
                            v = fmaf(-f1, sh[(kc + 1) * 132 + c], v);
                            v = fmaf(-f2, sh[(kc + 2) * 132 + c], v);
                            v = fmaf(-f3, sh[(kc + 3) * 132 + c], v);
                            sh[r * 132 + c] = v;
                        }
                    }
                }                           // chunk fully <= kc+3: dead, skip
            }
        }
        __syncthreads();
        for (int i = tid; i < 64 * 64; i += 1024) {
            int kk = i >> 6, d = i & 63;
            thetaT[i] = sh[d * 132 + 64 + kk];
        }
    } else {
        // ---------------- enc: 16 nodes/block, one node per wave ------------
        const int node0 = (blockIdx.x - 1) * 16;
        sh[tid]        = x[node0 * D_IN + tid];
        sh[tid + 1024] = x[node0 * D_IN + 1024 + tid];
        __syncthreads();
        const int nl = tid >> 6, lane = tid & 63;
        const int node = node0 + nl;
        const float* xr = &sh[nl * D_IN];   // wave-uniform reads -> LDS broadcast
        float acc = encb[lane];
#pragma unroll
        for (int k = 0; k < D_IN; ++k) acc = fmaf(xr[k], encW[k * D + lane], acc);
        b[node * D + lane]  = acc;
        x0[node * D + lane] = acc;
        t0[node * D + lane] = fabsf(acc) + acc;
        // ---------------- count incoming edges ------------------------------
        int e = (blockIdx.x - 1) * 1024 + tid;
        const int stride = 625 * 1024;
        for (; e < N_EDGES; e += stride) atomicAdd(&counts[dst[e]], 1);
    }
}

// ---------------------------------------------------------------------------
// Exclusive scan of counts -> rowptr/cursor.  1024 threads x 10 serial each,
// shfl wave-scan + 16-wave LDS combine: 2 barriers total.
// ---------------------------------------------------------------------------
__global__ void __launch_bounds__(1024) scan_kernel(
    const int* __restrict__ counts, int* __restrict__ rowptr,
    int* __restrict__ cursor) {
    __shared__ int wtot[16];
    const int tid = threadIdx.x;
    const int base = tid * 10;
    int c[10];
    int T = 0;
#pragma unroll
    for (int j = 0; j < 10; ++j) {
        int idx = base + j;
        c[j] = (idx < N_NODES) ? counts[idx] : 0;
        T += c[j];
    }
    int incl = T;                            // wave-inclusive scan
#pragma unroll
    for (int o = 1; o < 64; o <<= 1) {
        int v = __shfl_up(incl, o, 64);
        if ((tid & 63) >= o) incl += v;
    }
    const int wv = tid >> 6;
    if ((tid & 63) == 63) wtot[wv] = incl;
    __syncthreads();
    int wpre = 0;
#pragma unroll
    for (int w2 = 0; w2 < 16; ++w2) wpre += (w2 < wv) ? wtot[w2] : 0;
    int run = wpre + (incl - T);             // global exclusive offset
#pragma unroll
    for (int j = 0; j < 10; ++j) {
        int idx = base + j;
        if (idx < N_NODES) { rowptr[idx] = run; cursor[idx] = run; }
        run += c[j];
    }
    if (tid == 1023) rowptr[N_NODES] = run;  // == N_EDGES
}

// ---------------------------------------------------------------------------
// Scatter: edata.x packs src (low 16 bits) | dstLocal = dst%16 (bits 20..23);
// edata.y = weight bits.  Blocks of 16 nodes are 16-aligned so dstLocal is
// consistent for the consuming g_kernel.
// ---------------------------------------------------------------------------
__global__ void scatter_kernel(const int* __restrict__ src, const int* __restrict__ dst,
                               const float* __restrict__ ew, int* __restrict__ cursor,
                               uint2* __restrict__ edata) {
    int e = blockIdx.x * blockDim.x + threadIdx.x;
    const int stride = gridDim.x * blockDim.x;
    for (; e < N_EDGES; e += stride) {
        int d = dst[e];
        int p = atomicAdd(&cursor[d], 1);
        unsigned packed = (unsigned)src[e] | ((unsigned)(d & 15) << 20);
        edata[p] = make_uint2(packed, __float_as_uint(ew[e]));
    }
}

// ---------------------------------------------------------------------------
// Edge-pooled fused g: one block = 16 consecutive nodes = one contiguous CSR
// edge range (~512 edges).  8 waves consume pooled edges round-robin with
// unroll-8 (iterations fully independent -> loads stream), accumulating into
// LDS S[16][64] via native ds_add_f32 (row access = free 2-way bank alias).
// Then each wave applies Theta to 2 nodes from LDS (broadcast reads).
// Removes the per-wave serial degree chain and the wave-level degree
// straggler tax (block workload variance ~sqrt(512)/512 = 4%).
// ---------------------------------------------------------------------------
__global__ void __launch_bounds__(512) g_kernel(
    const int* __restrict__ rowptr, const uint2* __restrict__ edata,
    const float* __restrict__ t_in, const float* __restrict__ b,
    const float* __restrict__ thetaT, float* __restrict__ F,
    float* __restrict__ Xnext, float* __restrict__ t_out) {
    __shared__ float Th[D * D];     // 16 KB
    __shared__ float S[16][D];      // 4 KB
    const int tid = threadIdx.x;
#pragma unroll
    for (int i = 0; i < 2; ++i)              // 4096 floats / 512 thr = 2 float4
        *(float4*)&Th[(i * 512 + tid) * 4] = *(const float4*)&thetaT[(i * 512 + tid) * 4];
    ((float2*)&S[0][0])[tid] = make_float2(0.f, 0.f);   // zero 1024 floats
    const int ln = tid & 63, wv = tid >> 6;  // 8 waves
    const int node0 = blockIdx.x * 16;
    const int estart = rowptr[node0];
    const int eend   = rowptr[node0 + 16];
    __syncthreads();

    // ---- edge-parallel gather+accumulate: wave wv takes edges wv, wv+8, ...
    int e = estart + wv;
    for (; e + 56 < eend; e += 64) {         // unroll-8 (wave stride 8)
        uint2 a0 = edata[e +  0], a1 = edata[e +  8], a2 = edata[e + 16], a3 = edata[e + 24];
        uint2 a4 = edata[e + 32], a5 = edata[e + 40], a6 = edata[e + 48], a7 = edata[e + 56];
        float v0 = t_in[(a0.x & 0xFFFFu) * D + ln];
        float v1 = t_in[(a1.x & 0xFFFFu) * D + ln];
        float v2 = t_in[(a2.x & 0xFFFFu) * D + ln];
        float v3 = t_in[(a3.x & 0xFFFFu) * D + ln];
        float v4 = t_in[(a4.x & 0xFFFFu) * D + ln];
        float v5 = t_in[(a5.x & 0xFFFFu) * D + ln];
        float v6 = t_in[(a6.x & 0xFFFFu) * D + ln];
        float v7 = t_in[(a7.x & 0xFFFFu) * D + ln];
        atomicAdd(&S[a0.x >> 20][ln], v0 * __uint_as_float(a0.y));
        atomicAdd(&S[a1.x >> 20][ln], v1 * __uint_as_float(a1.y));
        atomicAdd(&S[a2.x >> 20][ln], v2 * __uint_as_float(a2.y));
        atomicAdd(&S[a3.x >> 20][ln], v3 * __uint_as_float(a3.y));
        atomicAdd(&S[a4.x >> 20][ln], v4 * __uint_as_float(a4.y));
        atomicAdd(&S[a5.x >> 20][ln], v5 * __uint_as_float(a5.y));
        atomicAdd(&S[a6.x >> 20][ln], v6 * __uint_as_float(a6.y));
        atomicAdd(&S[a7.x >> 20][ln], v7 * __uint_as_float(a7.y));
    }
    for (; e < eend; e += 8) {
        uint2 a = edata[e];
        float v = t_in[(a.x & 0xFFFFu) * D + ln];
        atomicAdd(&S[a.x >> 20][ln], v * __uint_as_float(a.y));
    }
    __syncthreads();

    // ---- matvec: wave wv handles nodes 2wv and 2wv+1 from LDS S ----
#pragma unroll
    for (int nn = 0; nn < 2; ++nn) {
        const int nl = wv * 2 + nn;
        const int node = node0 + nl;
        float r = 0.0f;
#pragma unroll
        for (int k = 0; k < D; ++k)          // S[nl][k] wave-uniform -> broadcast
            r = fmaf(S[nl][k], Th[k * D + ln], r);
        const float bb = b[node * D + ln];
        const float v = bb + 0.5f * r;
        F[node * D + ln] = v;
        if (Xnext) Xnext[node * D + ln] = v;
        if (t_out) t_out[node * D + ln] = fabsf(v) + bb;
    }
}

// ---------------------------------------------------------------------------
// Anderson: per-block partials of the GG upper triangle (15 entries) in f64.
// float4 streams (10 per iteration) for load efficiency; no global atomics.
// ---------------------------------------------------------------------------
__global__ void gg_kernel(const float* __restrict__ Xb, const float* __restrict__ Fb,
                          double* __restrict__ GGpart) {
    __shared__ double swave[4][16];
    double acc[15];
#pragma unroll
    for (int p = 0; p < 15; p++) acc[p] = 0.0;
    int idx = blockIdx.x * blockDim.x + threadIdx.x;
    const int stride = gridDim.x * blockDim.x;
    for (int i = idx; i < NM / 4; i += stride) {
        float4 g[5];
#pragma unroll
        for (int j = 0; j < 5; j++) {
            const float4 f = ((const float4*)(Fb + j * NM))[i];
            const float4 xv = ((const float4*)(Xb + j * NM))[i];
            g[j] = make_float4(f.x - xv.x, f.y - xv.y, f.z - xv.z, f.w - xv.w);
        }
        int p = 0;
#pragma unroll
        for (int a = 0; a < 5; a++)
#pragma unroll
            for (int bq = a; bq < 5; bq++) {
                acc[p] += (double)g[a].x * (double)g[bq].x
                        + (double)g[a].y * (double)g[bq].y
                        + (double)g[a].z * (double)g[bq].z
                        + (double)g[a].w * (double)g[bq].w;
                p++;
            }
    }
#pragma unroll
    for (int p = 0; p < 15; p++)
        for (int o = 32; o > 0; o >>= 1) acc[p] += __shfl_down(acc[p], o, 64);
    const int wv = threadIdx.x >> 6;
    if ((threadIdx.x & 63) == 0) {
#pragma unroll
        for (int p = 0; p < 15; p++) swave[wv][p] = acc[p];
    }
    __syncthreads();
    if (threadIdx.x < 15) {
        double s = swave[0][threadIdx.x] + swave[1][threadIdx.x] +
                   swave[2][threadIdx.x] + swave[3][threadIdx.x];
        GGpart[blockIdx.x * 16 + threadIdx.x] = s;
    }
}

// ---------------------------------------------------------------------------
// FUSED Anderson combine: every block reduces GGpart identically (bitwise-
// same result), thread 0 solves the 5x5 in f64, all threads combine
// Xk = sum_j a_j F[j] and (optionally) t = |Xk| + b.
// ---------------------------------------------------------------------------
__global__ void __launch_bounds__(256) acomb_kernel(
    const double* __restrict__ GGpart, const float* __restrict__ Fb,
    const float* __restrict__ b, float* __restrict__ Xk,
    float* __restrict__ t) {
    __shared__ double GG[16];
    __shared__ float as[5];
    const int tid = threadIdx.x;
    {   // ---- reduce GGpart: entry p = tid>>4, lane-in-group g = tid&15 ----
        const int p = tid >> 4;
        const int g = tid & 15;
        double s = 0.0;
        if (p < 15) {
            for (int blk = g; blk < GG_BLOCKS; blk += 16) s += GGpart[blk * 16 + p];
        }
#pragma unroll
        for (int o = 8; o > 0; o >>= 1) s += __shfl_down(s, o, 16);
        if (g == 0 && p < 15) GG[p] = s;
    }
    __syncthreads();
    if (tid == 0) {   // ---- 5x5 f64 solve with partial pivoting ----
        double A[5][5], rhs[5];
        int q = 0;
        for (int r = 0; r < 5; r++)
            for (int c = r; c < 5; c++) { double v = GG[q++]; A[r][c] = v; A[c][r] = v; }
        for (int i = 0; i < 5; i++) { A[i][i] += 1e-4; rhs[i] = 1.0; }
        for (int i = 0; i < 5; i++) {
            int piv = i; double best = fabs(A[i][i]);
            for (int r = i + 1; r < 5; r++) {
                double v = fabs(A[r][i]);
                if (v > best) { best = v; piv = r; }
            }
            if (piv != i) {
                for (int c = 0; c < 5; c++) { double tmp = A[i][c]; A[i][c] = A[piv][c]; A[piv][c] = tmp; }
                double tr = rhs[i]; rhs[i] = rhs[piv]; rhs[piv] = tr;
            }
            double inv = 1.0 / A[i][i];
            for (int c = 0; c < 5; c++) A[i][c] *= inv;
            rhs[i] *= inv;
            for (int r = 0; r < 5; r++)
                if (r != i) {
                    double f = A[r][i];
                    for (int c = 0; c < 5; c++) A[r][c] -= f * A[i][c];
                    rhs[r] -= f * rhs[i];
                }
        }
        double ssum = rhs[0] + rhs[1] + rhs[2] + rhs[3] + rhs[4];
        for (int j = 0; j < 5; j++) as[j] = (float)(rhs[j] / ssum);
    }
    __syncthreads();
    // ---- combine ----
    int i = blockIdx.x * blockDim.x + tid;
    if (i >= NM / 4) return;
    float4 r = {0.f, 0.f, 0.f, 0.f};
#pragma unroll
    for (int j = 0; j < 5; j++) {
        const float4 f = ((const float4*)(Fb + j * NM))[i];
        float aj = as[j];
        r.x = fmaf(aj, f.x, r.x);
        r.y = fmaf(aj, f.y, r.y);
        r.z = fmaf(aj, f.z, r.z);
        r.w = fmaf(aj, f.w, r.w);
    }
    ((float4*)Xk)[i] = r;
    if (t) {
        const float4 bv = ((const float4*)b)[i];
        float4 tv;
        tv.x = fabsf(r.x) + bv.x;
        tv.y = fabsf(r.y) + bv.y;
        tv.z = fabsf(r.z) + bv.z;
        tv.w = fabsf(r.w) + bv.w;
        ((float4*)t)[i] = tv;
    }
}

// ---------------------------------------------------------------------------
// out[node][o] = sum_d relu(u[node][d]) * decW[d][o]
// ---------------------------------------------------------------------------
__global__ void out_kernel(const float* __restrict__ u, const float* __restrict__ decW,
                           float* __restrict__ out) {
    __shared__ float W[D * D_OUT];
    __shared__ float rows[16][D + 1];
    const int tid = threadIdx.x;
    for (int i = tid; i < D * D_OUT; i += 256) W[i] = decW[i];
    const int node0 = blockIdx.x * 16;
    for (int i = tid; i < 16 * D; i += 256) {
        int n = i >> 6, d = i & 63;
        rows[n][d] = u[(node0 + n) * D + d];
    }
    __syncthreads();
    const int n = tid >> 4, o = tid & 15;
    float acc = 0.0f;
#pragma unroll
    for (int d2 = 0; d2 < D; d2++)
        acc = fmaf(fmaxf(rows[n][d2], 0.0f), W[d2 * D_OUT + o], acc);
    out[(node0 + n) * D_OUT + o] = acc;
}

// ---------------------------------------------------------------------------
extern "C" void kernel_launch(void* const* d_in, const int* in_sizes, int n_in,
                              void* d_out, int out_size, void* d_ws, size_t ws_size,
                              hipStream_t stream) {
    const float* x    = (const float*)d_in[0];
    const int*   ei   = (const int*)d_in[1];
    const float* ew   = (const float*)d_in[2];
    const float* encW = (const float*)d_in[3];
    const float* encb = (const float*)d_in[4];
    const float* cayB = (const float*)d_in[5];
    const float* decW = (const float*)d_in[6];
    float* out = (float*)d_out;
    const int* src = ei;
    const int* dst = ei + N_EDGES;

    char* w = (char*)d_ws;
    double* GGpart = (double*)w;                       // 32768 B
    float*  thetaT = (float*)(w + 33024);              // 16384 B
    int*    counts = (int*)(w + 49408);                // 40000 B
    int*    rowptr = (int*)(w + 89408);                // 40004 B -> pad to 40192
    int*    cursor = (int*)(w + 129600);               // 40000 B -> pad to 40384
    uint2*  edata  = (uint2*)(w + 169984);             // 2560000 B
    float*  b   = (float*)(w + 2729984);
    float*  t0  = b + NM;
    float*  t1  = t0 + NM;
    float*  Xb  = t1 + NM;                             // 5 slots
    float*  Fb  = Xb + 5 * NM;                         // 5 slots

    // setup: theta (block 0) || enc + count (blocks 1..625)
    hipMemsetAsync(counts, 0, N_NODES * sizeof(int), stream);
    setup_kernel<<<626, 1024, 0, stream>>>(cayB, thetaT, x, encW, encb,
                                           b, Xb, t0, dst, counts);
    scan_kernel<<<1, 1024, 0, stream>>>(counts, rowptr, cursor);
    scatter_kernel<<<512, 256, 0, stream>>>(src, dst, ew, cursor, edata);

    const int EW_BLOCKS = (NM / 4 + 255) / 256;   // 625

    // init phase: F[i] = g(X[i]); X[i+1] = F[i]; t ping-pong (g_i reads t_{i%2})
    for (int i = 0; i < 5; i++) {
        float* tin  = (i & 1) ? t1 : t0;
        float* tout = (i < 4) ? ((i & 1) ? t0 : t1) : nullptr;
        g_kernel<<<N_NODES / 16, 512, 0, stream>>>(
            rowptr, edata, tin, b, thetaT, Fb + i * NM,
            (i < 4) ? (Xb + (i + 1) * NM) : nullptr, tout);
    }

    // Anderson phase: gg -> fused (reduce+solve+combine) -> g
    // Last combine (k=4) skips the dead t0 write (no g follows).
    for (int k = 0; k < 5; k++) {
        gg_kernel<<<GG_BLOCKS, 256, 0, stream>>>(Xb, Fb, GGpart);
        acomb_kernel<<<EW_BLOCKS, 256, 0, stream>>>(
            GGpart, Fb, b, Xb + k * NM, (k < 4) ? t0 : nullptr);
        if (k < 4)
            g_kernel<<<N_NODES / 16, 512, 0, stream>>>(
                rowptr, edata, t0, b, thetaT, Fb + k * NM, nullptr, nullptr);
    }

    out_kernel<<<N_NODES / 16, 256, 0, stream>>>(Xb + 4 * NM, decW, out);
}

// Round 17
// 421.650 us; speedup vs baseline: 3.4983x; 3.4983x over previous
//
#include <hip/hip_runtime.h>
#include <math.h>

#define N_NODES 10000
#define N_EDGES 320000
#define D 64
#define D_IN 128
#define D_OUT 16
#define NM (N_NODES * D)   // 640000 elements per state vector
#define GG_BLOCKS 256

// ---------------------------------------------------------------------------
// Fused setup: block 0 computes Theta = (I+Om)^-1 (I-Om); blocks 1..625 do
// enc (16 nodes each, one node per wave) + edge counting.
// Theta via 4x4-BLOCKED no-pivot Gauss-Jordan, 16 steps x 3 barriers.
// Phase A (4x4 diag-block inverse) is WAVE-PARALLEL via __shfl.
// No-pivot validity: every Schur complement of A = I + skew has symmetric
// part >= I, as does each leading 4x4 block.
// Theta stored TRANSPOSED: thetaT[k*64 + d] = Theta[d][k].
// ---------------------------------------------------------------------------
__global__ void __launch_bounds__(1024) setup_kernel(
    const float* __restrict__ B, float* __restrict__ thetaT,
    const float* __restrict__ x, const float* __restrict__ encW,
    const float* __restrict__ encb, float* __restrict__ b,
    float* __restrict__ x0, float* __restrict__ t0,
    const int* __restrict__ dst, int* __restrict__ counts) {
    __shared__ float sh[64 * 132 + 16];     // M (stride 132) + Dinv
    const int tid = threadIdx.x;

    if (blockIdx.x == 0) {
        float* Dinv = &sh[64 * 132];
        for (int i = tid; i < 64 * 128; i += 1024) {
            int r = i >> 7, c = i & 127;
            float v;
            if (c < 64) {
                float om = 0.5f * (B[r * 64 + c] - B[c * 64 + r]);
                v = om + (r == c ? 1.0f : 0.0f);
            } else {
                int c2 = c - 64;
                float om = 0.5f * (B[r * 64 + c2] - B[c2 * 64 + r]);
                v = -om + (r == c2 ? 1.0f : 0.0f);
            }
            sh[r * 132 + c] = v;
        }
        const int r  = tid >> 4;            // owned row (64)
        const int cb = (tid & 15) * 8;      // owned 8-col chunk (16)

        for (int kb = 0; kb < 16; ++kb) {
            const int kc = kb * 4;
            __syncthreads();
            // A: lanes 0..15 invert the 4x4 diag block, in-place GJ via shfl.
            if (tid < 16) {
                const int i = tid >> 2, j = tid & 3;
                float a = sh[(kc + i) * 132 + kc + j];
#pragma unroll
                for (int p = 0; p < 4; ++p) {
                    float app = __shfl(a, p * 5, 16);
                    float apj = __shfl(a, p * 4 + j, 16);
                    float aip = __shfl(a, i * 4 + p, 16);
                    float d = 1.0f / app;
                    float na;
                    if (i == p)      na = (j == p) ? d : a * d;
                    else if (j == p) na = -a * d;
                    else             na = fmaf(-aip * d, apj, a);
                    a = na;
                }
                Dinv[tid] = a;
            }
            __syncthreads();
            // B: pivot rows <- Dinv @ pivot rows, cols kc+4..127 (one col/thread)
            {
                int c = kc + 4 + tid;
                if (c < 128) {
                    float o0 = sh[(kc + 0) * 132 + c];
                    float o1 = sh[(kc + 1) * 132 + c];
                    float o2 = sh[(kc + 2) * 132 + c];
                    float o3 = sh[(kc + 3) * 132 + c];
#pragma unroll
                    for (int i = 0; i < 4; ++i) {
                        float n = Dinv[i * 4 + 0] * o0 + Dinv[i * 4 + 1] * o1 +
                                  Dinv[i * 4 + 2] * o2 + Dinv[i * 4 + 3] * o3;
                        sh[(kc + i) * 132 + c] = n;
                    }
                }
            }
            __syncthreads();
            // C: rank-4 eliminate rows outside block, cols > kc+3
            if (r < kc || r > kc + 3) {
                const float f0 = sh[r * 132 + kc + 0];
                const float f1 = sh[r * 132 + kc + 1];
                const float f2 = sh[r * 132 + kc + 2];
                const float f3 = sh[r * 132 + kc + 3];
                if (cb > kc + 3) {          // chunk fully beyond block: float4 path
#pragma unroll
                    for (int h = 0; h < 2; ++h) {
                        const int c = cb + h * 4;
                        float4 p0 = *(const float4*)&sh[(kc + 0) * 132 + c];
                        float4 p1 = *(const float4*)&sh[(kc + 1) * 132 + c];
                        float4 p2 = *(const float4*)&sh[(kc + 2) * 132 + c];
                        float4 p3 = *(const float4*)&sh[(kc + 3) * 132 + c];
                        float4 v  = *(float4*)&sh[r * 132 + c];
                        v.x = fmaf(-f3, p3.x, fmaf(-f2, p2.x, fmaf(-f1, p1.x, fmaf(-f0, p0.x, v.x))));
                        v.y = fmaf(-f3, p3.y, fmaf(-f2, p2.y, fmaf(-f1, p1.y, fmaf(-f0, p0.y, v.y))));
                        v.z = fmaf(-f3, p3.z, fmaf(-f2, p2.z, fmaf(-f1, p1.z, fmaf(-f0, p0.z, v.z))));
                        v.w = fmaf(-f3, p3.w, fmaf(-f2, p2.w, fmaf(-f1, p1.w, fmaf(-f0, p0.w, v.w))));
                        *(float4*)&sh[r * 132 + c] = v;
                    }
                } else if (cb + 7 > kc + 3) {  // straddling chunk: predicated scalar
#pragma unroll
                    for (int j = 0; j < 8; ++j) {
                        const int c = cb + j;
                        if (c > kc + 3) {
                            float v = sh[r * 132 + c];
                            v = fmaf(-f0, sh[(kc + 0) * 132 + c], v);
                            v = fmaf(-f1, sh[(kc + 1) * 132 + c], v);
                            v = fmaf(-f2, sh[(kc + 2) * 132 + c], v);
                            v = fmaf(-f3, sh[(kc + 3) * 132 + c], v);
                            sh[r * 132 + c] = v;
                        }
                    }
                }                           // chunk fully <= kc+3: dead, skip
            }
        }
        __syncthreads();
        for (int i = tid; i < 64 * 64; i += 1024) {
            int kk = i >> 6, d = i & 63;
            thetaT[i] = sh[d * 132 + 64 + kk];
        }
    } else {
        // ---------------- enc: 16 nodes/block, one node per wave ------------
        const int node0 = (blockIdx.x - 1) * 16;
        sh[tid]        = x[node0 * D_IN + tid];
        sh[tid + 1024] = x[node0 * D_IN + 1024 + tid];
        __syncthreads();
        const int nl = tid >> 6, lane = tid & 63;
        const int node = node0 + nl;
        const float* xr = &sh[nl * D_IN];   // wave-uniform reads -> LDS broadcast
        float acc = encb[lane];
#pragma unroll
        for (int k = 0; k < D_IN; ++k) acc = fmaf(xr[k], encW[k * D + lane], acc);
        b[node * D + lane]  = acc;
        x0[node * D + lane] = acc;
        t0[node * D + lane] = fabsf(acc) + acc;
        // ---------------- count incoming edges ------------------------------
        int e = (blockIdx.x - 1) * 1024 + tid;
        const int stride = 625 * 1024;
        for (; e < N_EDGES; e += stride) atomicAdd(&counts[dst[e]], 1);
    }
}

// ---------------------------------------------------------------------------
// Exclusive scan of counts -> rowptr/cursor.  1024 threads x 10 serial each,
// shfl wave-scan + 16-wave LDS combine: 2 barriers total.
// ---------------------------------------------------------------------------
__global__ void __launch_bounds__(1024) scan_kernel(
    const int* __restrict__ counts, int* __restrict__ rowptr,
    int* __restrict__ cursor) {
    __shared__ int wtot[16];
    const int tid = threadIdx.x;
    const int base = tid * 10;
    int c[10];
    int T = 0;
#pragma unroll
    for (int j = 0; j < 10; ++j) {
        int idx = base + j;
        c[j] = (idx < N_NODES) ? counts[idx] : 0;
        T += c[j];
    }
    int incl = T;                            // wave-inclusive scan
#pragma unroll
    for (int o = 1; o < 64; o <<= 1) {
        int v = __shfl_up(incl, o, 64);
        if ((tid & 63) >= o) incl += v;
    }
    const int wv = tid >> 6;
    if ((tid & 63) == 63) wtot[wv] = incl;
    __syncthreads();
    int wpre = 0;
#pragma unroll
    for (int w2 = 0; w2 < 16; ++w2) wpre += (w2 < wv) ? wtot[w2] : 0;
    int run = wpre + (incl - T);             // global exclusive offset
#pragma unroll
    for (int j = 0; j < 10; ++j) {
        int idx = base + j;
        if (idx < N_NODES) { rowptr[idx] = run; cursor[idx] = run; }
        run += c[j];
    }
    if (tid == 1023) rowptr[N_NODES] = run;  // == N_EDGES
}

__global__ void scatter_kernel(const int* __restrict__ src, const int* __restrict__ dst,
                               const float* __restrict__ ew, int* __restrict__ cursor,
                               uint2* __restrict__ edata) {
    int e = blockIdx.x * blockDim.x + threadIdx.x;
    const int stride = gridDim.x * blockDim.x;
    for (; e < N_EDGES; e += stride) {
        int p = atomicAdd(&cursor[dst[e]], 1);
        edata[p] = make_uint2((unsigned)src[e], __float_as_uint(ew[e]));
    }
}

// ---------------------------------------------------------------------------
// Fused g (round-14 proven form): F[node] = b + 0.5*Theta @ (A t_in)[node],
// one wave per node.  512-thr blocks (8 nodes) amortize Th staging; CSR
// gather unroll-8; 64x64 matvec via __shfl broadcast (no Srow LDS).
// Optional dual-writes: Xnext = F (init history), t_out = |F| + b (next t).
// ---------------------------------------------------------------------------
__global__ void __launch_bounds__(512) g_kernel(
    const int* __restrict__ rowptr, const uint2* __restrict__ edata,
    const float* __restrict__ t_in, const float* __restrict__ b,
    const float* __restrict__ thetaT, float* __restrict__ F,
    float* __restrict__ Xnext, float* __restrict__ t_out) {
    __shared__ float Th[D * D];
    const int tid = threadIdx.x;
#pragma unroll
    for (int i = 0; i < 2; ++i)              // 4096 floats / 512 thr = 2 float4
        *(float4*)&Th[(i * 512 + tid) * 4] = *(const float4*)&thetaT[(i * 512 + tid) * 4];
    const int ln = tid & 63, wv = tid >> 6;  // 8 waves
    const int node = blockIdx.x * 8 + wv;
    __syncthreads();

    float acc = 0.0f;
    int e = rowptr[node];
    const int end = rowptr[node + 1];
    for (; e + 7 < end; e += 8) {            // unroll-8: 8 gathers in flight
        uint2 a0 = edata[e + 0], a1 = edata[e + 1], a2 = edata[e + 2], a3 = edata[e + 3];
        uint2 a4 = edata[e + 4], a5 = edata[e + 5], a6 = edata[e + 6], a7 = edata[e + 7];
        float v0 = t_in[a0.x * D + ln];
        float v1 = t_in[a1.x * D + ln];
        float v2 = t_in[a2.x * D + ln];
        float v3 = t_in[a3.x * D + ln];
        float v4 = t_in[a4.x * D + ln];
        float v5 = t_in[a5.x * D + ln];
        float v6 = t_in[a6.x * D + ln];
        float v7 = t_in[a7.x * D + ln];
        acc = fmaf(__uint_as_float(a0.y), v0, acc);
        acc = fmaf(__uint_as_float(a1.y), v1, acc);
        acc = fmaf(__uint_as_float(a2.y), v2, acc);
        acc = fmaf(__uint_as_float(a3.y), v3, acc);
        acc = fmaf(__uint_as_float(a4.y), v4, acc);
        acc = fmaf(__uint_as_float(a5.y), v5, acc);
        acc = fmaf(__uint_as_float(a6.y), v6, acc);
        acc = fmaf(__uint_as_float(a7.y), v7, acc);
    }
    for (; e + 3 < end; e += 4) {
        uint2 a0 = edata[e + 0], a1 = edata[e + 1], a2 = edata[e + 2], a3 = edata[e + 3];
        float v0 = t_in[a0.x * D + ln];
        float v1 = t_in[a1.x * D + ln];
        float v2 = t_in[a2.x * D + ln];
        float v3 = t_in[a3.x * D + ln];
        acc = fmaf(__uint_as_float(a0.y), v0, acc);
        acc = fmaf(__uint_as_float(a1.y), v1, acc);
        acc = fmaf(__uint_as_float(a2.y), v2, acc);
        acc = fmaf(__uint_as_float(a3.y), v3, acc);
    }
    for (; e < end; ++e) {
        uint2 a = edata[e];
        acc = fmaf(__uint_as_float(a.y), t_in[a.x * D + ln], acc);
    }

    float r = 0.0f;
#pragma unroll
    for (int k = 0; k < D; ++k) {           // S[k] broadcast via shuffle
        float sk = __shfl(acc, k, 64);
        r = fmaf(sk, Th[k * D + ln], r);
    }
    const float bb = b[node * D + ln];
    const float v = bb + 0.5f * r;
    F[node * D + ln] = v;
    if (Xnext) Xnext[node * D + ln] = v;
    if (t_out) t_out[node * D + ln] = fabsf(v) + bb;
}

// ---------------------------------------------------------------------------
// Anderson: per-block partials of the GG upper triangle (15 entries) in f64.
// float4 streams (10 per iteration) for load efficiency; no global atomics.
// ---------------------------------------------------------------------------
__global__ void gg_kernel(const float* __restrict__ Xb, const float* __restrict__ Fb,
                          double* __restrict__ GGpart) {
    __shared__ double swave[4][16];
    double acc[15];
#pragma unroll
    for (int p = 0; p < 15; p++) acc[p] = 0.0;
    int idx = blockIdx.x * blockDim.x + threadIdx.x;
    const int stride = gridDim.x * blockDim.x;
    for (int i = idx; i < NM / 4; i += stride) {
        float4 g[5];
#pragma unroll
        for (int j = 0; j < 5; j++) {
            const float4 f = ((const float4*)(Fb + j * NM))[i];
            const float4 xv = ((const float4*)(Xb + j * NM))[i];
            g[j] = make_float4(f.x - xv.x, f.y - xv.y, f.z - xv.z, f.w - xv.w);
        }
        int p = 0;
#pragma unroll
        for (int a = 0; a < 5; a++)
#pragma unroll
            for (int bq = a; bq < 5; bq++) {
                acc[p] += (double)g[a].x * (double)g[bq].x
                        + (double)g[a].y * (double)g[bq].y
                        + (double)g[a].z * (double)g[bq].z
                        + (double)g[a].w * (double)g[bq].w;
                p++;
            }
    }
#pragma unroll
    for (int p = 0; p < 15; p++)
        for (int o = 32; o > 0; o >>= 1) acc[p] += __shfl_down(acc[p], o, 64);
    const int wv = threadIdx.x >> 6;
    if ((threadIdx.x & 63) == 0) {
#pragma unroll
        for (int p = 0; p < 15; p++) swave[wv][p] = acc[p];
    }
    __syncthreads();
    if (threadIdx.x < 15) {
        double s = swave[0][threadIdx.x] + swave[1][threadIdx.x] +
                   swave[2][threadIdx.x] + swave[3][threadIdx.x];
        GGpart[blockIdx.x * 16 + threadIdx.x] = s;
    }
}

// ---------------------------------------------------------------------------
// FUSED Anderson combine: every block reduces GGpart identically (bitwise-
// same result), thread 0 solves the 5x5 in f64, all threads combine
// Xk = sum_j a_j F[j] and (optionally) t = |Xk| + b.
// ---------------------------------------------------------------------------
__global__ void __launch_bounds__(256) acomb_kernel(
    const double* __restrict__ GGpart, const float* __restrict__ Fb,
    const float* __restrict__ b, float* __restrict__ Xk,
    float* __restrict__ t) {
    __shared__ double GG[16];
    __shared__ float as[5];
    const int tid = threadIdx.x;
    {   // ---- reduce GGpart: entry p = tid>>4, lane-in-group g = tid&15 ----
        const int p = tid >> 4;
        const int g = tid & 15;
        double s = 0.0;
        if (p < 15) {
            for (int blk = g; blk < GG_BLOCKS; blk += 16) s += GGpart[blk * 16 + p];
        }
#pragma unroll
        for (int o = 8; o > 0; o >>= 1) s += __shfl_down(s, o, 16);
        if (g == 0 && p < 15) GG[p] = s;
    }
    __syncthreads();
    if (tid == 0) {   // ---- 5x5 f64 solve with partial pivoting ----
        double A[5][5], rhs[5];
        int q = 0;
        for (int r = 0; r < 5; r++)
            for (int c = r; c < 5; c++) { double v = GG[q++]; A[r][c] = v; A[c][r] = v; }
        for (int i = 0; i < 5; i++) { A[i][i] += 1e-4; rhs[i] = 1.0; }
        for (int i = 0; i < 5; i++) {
            int piv = i; double best = fabs(A[i][i]);
            for (int r = i + 1; r < 5; r++) {
                double v = fabs(A[r][i]);
                if (v > best) { best = v; piv = r; }
            }
            if (piv != i) {
                for (int c = 0; c < 5; c++) { double tmp = A[i][c]; A[i][c] = A[piv][c]; A[piv][c] = tmp; }
                double tr = rhs[i]; rhs[i] = rhs[piv]; rhs[piv] = tr;
            }
            double inv = 1.0 / A[i][i];
            for (int c = 0; c < 5; c++) A[i][c] *= inv;
            rhs[i] *= inv;
            for (int r = 0; r < 5; r++)
                if (r != i) {
                    double f = A[r][i];
                    for (int c = 0; c < 5; c++) A[r][c] -= f * A[i][c];
                    rhs[r] -= f * rhs[i];
                }
        }
        double ssum = rhs[0] + rhs[1] + rhs[2] + rhs[3] + rhs[4];
        for (int j = 0; j < 5; j++) as[j] = (float)(rhs[j] / ssum);
    }
    __syncthreads();
    // ---- combine ----
    int i = blockIdx.x * blockDim.x + tid;
    if (i >= NM / 4) return;
    float4 r = {0.f, 0.f, 0.f, 0.f};
#pragma unroll
    for (int j = 0; j < 5; j++) {
        const float4 f = ((const float4*)(Fb + j * NM))[i];
        float aj = as[j];
        r.x = fmaf(aj, f.x, r.x);
        r.y = fmaf(aj, f.y, r.y);
        r.z = fmaf(aj, f.z, r.z);
        r.w = fmaf(aj, f.w, r.w);
    }
    ((float4*)Xk)[i] = r;
    if (t) {
        const float4 bv = ((const float4*)b)[i];
        float4 tv;
        tv.x = fabsf(r.x) + bv.x;
        tv.y = fabsf(r.y) + bv.y;
        tv.z = fabsf(r.z) + bv.z;
        tv.w = fabsf(r.w) + bv.w;
        ((float4*)t)[i] = tv;
    }
}

// ---------------------------------------------------------------------------
// out[node][o] = sum_d relu(u[node][d]) * decW[d][o]
// ---------------------------------------------------------------------------
__global__ void out_kernel(const float* __restrict__ u, const float* __restrict__ decW,
                           float* __restrict__ out) {
    __shared__ float W[D * D_OUT];
    __shared__ float rows[16][D + 1];
    const int tid = threadIdx.x;
    for (int i = tid; i < D * D_OUT; i += 256) W[i] = decW[i];
    const int node0 = blockIdx.x * 16;
    for (int i = tid; i < 16 * D; i += 256) {
        int n = i >> 6, d = i & 63;
        rows[n][d] = u[(node0 + n) * D + d];
    }
    __syncthreads();
    const int n = tid >> 4, o = tid & 15;
    float acc = 0.0f;
#pragma unroll
    for (int d2 = 0; d2 < D; d2++)
        acc = fmaf(fmaxf(rows[n][d2], 0.0f), W[d2 * D_OUT + o], acc);
    out[(node0 + n) * D_OUT + o] = acc;
}

// ---------------------------------------------------------------------------
extern "C" void kernel_launch(void* const* d_in, const int* in_sizes, int n_in,
                              void* d_out, int out_size, void* d_ws, size_t ws_size,
                              hipStream_t stream) {
    const float* x    = (const float*)d_in[0];
    const int*   ei   = (const int*)d_in[1];
    const float* ew   = (const float*)d_in[2];
    const float* encW = (const float*)d_in[3];
    const float* encb = (const float*)d_in[4];
    const float* cayB = (const float*)d_in[5];
    const float* decW = (const float*)d_in[6];
    float* out = (float*)d_out;
    const int* src = ei;
    const int* dst = ei + N_EDGES;

    char* w = (char*)d_ws;
    double* GGpart = (double*)w;                       // 32768 B
    float*  thetaT = (float*)(w + 33024);              // 16384 B
    int*    counts = (int*)(w + 49408);                // 40000 B
    int*    rowptr = (int*)(w + 89408);                // 40004 B -> pad to 40192
    int*    cursor = (int*)(w + 129600);               // 40000 B -> pad to 40384
    uint2*  edata  = (uint2*)(w + 169984);             // 2560000 B
    float*  b   = (float*)(w + 2729984);
    float*  t0  = b + NM;
    float*  t1  = t0 + NM;
    float*  Xb  = t1 + NM;                             // 5 slots
    float*  Fb  = Xb + 5 * NM;                         // 5 slots

    // setup: theta (block 0) || enc + count (blocks 1..625)
    hipMemsetAsync(counts, 0, N_NODES * sizeof(int), stream);
    setup_kernel<<<626, 1024, 0, stream>>>(cayB, thetaT, x, encW, encb,
                                           b, Xb, t0, dst, counts);
    scan_kernel<<<1, 1024, 0, stream>>>(counts, rowptr, cursor);
    scatter_kernel<<<512, 256, 0, stream>>>(src, dst, ew, cursor, edata);

    const int EW_BLOCKS = (NM / 4 + 255) / 256;   // 625

    // init phase: F[i] = g(X[i]); X[i+1] = F[i]; t ping-pong (g_i reads t_{i%2})
    for (int i = 0; i < 5; i++) {
        float* tin  = (i & 1) ? t1 : t0;
        float* tout = (i < 4) ? ((i & 1) ? t0 : t1) : nullptr;
        g_kernel<<<N_NODES / 8, 512, 0, stream>>>(
            rowptr, edata, tin, b, thetaT, Fb + i * NM,
            (i < 4) ? (Xb + (i + 1) * NM) : nullptr, tout);
    }

    // Anderson phase: gg -> fused (reduce+solve+combine) -> g
    // Last combine (k=4) skips the dead t0 write (no g follows).
    for (int k = 0; k < 5; k++) {
        gg_kernel<<<GG_BLOCKS, 256, 0, stream>>>(Xb, Fb, GGpart);
        acomb_kernel<<<EW_BLOCKS, 256, 0, stream>>>(
            GGpart, Fb, b, Xb + k * NM, (k < 4) ? t0 : nullptr);
        if (k < 4)
            g_kernel<<<N_NODES / 8, 512, 0, stream>>>(
                rowptr, edata, t0, b, thetaT, Fb + k * NM, nullptr, nullptr);
    }

    out_kernel<<<N_NODES / 16, 256, 0, stream>>>(Xb + 4 * NM, decW, out);
}